// Round 20
// baseline (29.749 us; speedup 1.0000x reference)
//
#include <hip/hip_runtime.h>

namespace {

constexpr int kB = 256;
constexpr int kT = 1024;
constexpr int kC = 64;
constexpr int kSteps = 12;        // 4 burn-in + 8 span
constexpr int kRowStride = 136;   // 128B f16 row + 8B pad
constexpr int kMaxRows = 520;

typedef _Float16 half1_t;
typedef _Float16 half4_t __attribute__((ext_vector_type(4)));
typedef float    f32x4  __attribute__((ext_vector_type(4)));

__device__ __forceinline__ float wave_sum(float v) {
#pragma unroll
  for (int off = 32; off >= 1; off >>= 1) v += __shfl_xor(v, off, 64);
  return v;
}
// reduce across the 4 lanes {l, l^16, l^32, l^48} holding one column
__device__ __forceinline__ float chain_max(float v) {
  v = fmaxf(v, __shfl_xor(v, 16, 64));
  v = fmaxf(v, __shfl_xor(v, 32, 64));
  return v;
}
__device__ __forceinline__ float chain_sum(float v) {
  v += __shfl_xor(v, 16, 64);
  v += __shfl_xor(v, 32, 64);
  return v;
}

// 512 blocks x 256 threads, NO BARRIERS. Block (b,h): batch b, segments
// 64h..64h+63; wave wid owns 16 real segments (span 8, burn-in 4).
// Wave autonomy: wave wid's phase-2 + PE reads touch only LDS rows
// [128*wid, 128*wid+131]; it stages rows [128*wid, 128*wid+135] itself
// (8-row overlap with neighbor written twice with IDENTICAL bytes - benign).
// So each wave runs stage -> (own lgkmcnt) -> compute with zero block sync;
// early waves' MFMA overlaps late waves' HBM drain.
// Step math verified r12-r19 (absmax 0.0): D[mb]=sum_kb mfma(W'[mb][kb],P[kb]);
// P=cvt_f16(D*sc*E); delay-1 dead-beat pow2 renorm; W'=exp(U)/4; sacc+=eprev+2.
// Output fused: one atomicAdd per wave into out[b] (out zeroed by memsetAsync).
__global__ __launch_bounds__(256) void crf_fused(
    const float* __restrict__ x,    // [B,T,C]
    const float* __restrict__ U,    // [C,C]
    const float* __restrict__ bs,   // [C]
    const float* __restrict__ be,   // [C]
    const int*   __restrict__ y,    // [B,T]
    float*       __restrict__ out)  // [B] accumulated
{
  const int bid = blockIdx.x;
  const int tid = threadIdx.x;
  const int wid = tid >> 6;
  const int j   = tid & 63;

  __shared__ __align__(16) char els[kMaxRows * kRowStride];  // 70720 B

  const int b    = bid >> 1;
  const int h    = bid & 1;
  const int R1   = h ? 509 : 1;    // t of source row 0
  const int elo  = h ? 0 : 4;
  const int ehi  = h ? 514 : 515;
  const int eoff = h ? 0 : 4;      // e = (t - R1) + eoff
  const int maxn = h ? 514 : 511;  // last valid source row (t - R1)

  const float* xbase = x + (size_t)b * kT * kC;

  // ---- path-energy index loads (issued early) ----
  const int t0 = 512 * h + 2 * tid;
  const int* yrow = y + (size_t)b * kT;
  const int ym = (t0 > 0) ? yrow[t0 - 1] : 0;
  const int y0 = yrow[t0];
  const int y1 = yrow[t0 + 1];

  // ---- wave-local staging: rows [128*wid, 128*wid+135], 2 x 17-deep ----
  {
    const float* xs = xbase + (size_t)R1 * kC;
#define STAGE_BURST(U0, UN)                                                    \
    {                                                                          \
      f32x4 v[UN];                                                             \
      _Pragma("unroll")                                                        \
      for (int u = 0; u < UN; ++u) {                                           \
        const int g = (U0 + u) * 64 + j;                                       \
        int n = (128 * wid + (g >> 4)) - eoff;                                 \
        n = (n < 0) ? 0 : ((n > maxn) ? maxn : n);                             \
        v[u] = *reinterpret_cast<const f32x4*>(xs + (size_t)n * kC + (g & 15) * 4); \
      }                                                                        \
      _Pragma("unroll")                                                        \
      for (int u = 0; u < UN; ++u) {                                           \
        const int g = (U0 + u) * 64 + j;                                       \
        const int e  = 128 * wid + (g >> 4);                                   \
        const int k0 = g & 15;                                                 \
        half4_t hv;                                                            \
        hv[0] = (half1_t)__expf(v[u][0]);                                      \
        hv[1] = (half1_t)__expf(v[u][1]);                                      \
        hv[2] = (half1_t)__expf(v[u][2]);                                      \
        hv[3] = (half1_t)__expf(v[u][3]);                                      \
        const int sw = ((e >> 4) & 7) << 4;                                    \
        *reinterpret_cast<half4_t*>(els + e * kRowStride + ((k0 * 8) ^ sw)) = hv; \
      }                                                                        \
    }
    STAGE_BURST(0, 17)
    STAGE_BURST(17, 17)
#undef STAGE_BURST
  }

  // path-energy U terms (L1/L2-hot)
  const float peu1 = U[y0 * kC + y1];
  const float peu0 = U[ym * kC + y0];

  const int q = j >> 4;       // k/m quad selector
  const int r = j & 15;       // MFMA column = segment-within-wave
  const int c = 64 * h + 16 * wid + r;    // global segment id 0..127

  // ---- W' A-fragments: A[m=r][k=4q+i] of (mb,kb) = exp(U[16kb+k][16mb+m])/4
  half4_t W[4][4];
#pragma unroll
  for (int mb = 0; mb < 4; ++mb)
#pragma unroll
    for (int kb = 0; kb < 4; ++kb) {
      half4_t w;
#pragma unroll
      for (int i = 0; i < 4; ++i)
        w[i] = (half1_t)(0.25f * __expf(U[(16 * kb + 4 * q + i) * kC + 16 * mb + r]));
      W[mb][kb] = w;
    }

  float ebe[4][4];
#pragma unroll
  for (int mb = 0; mb < 4; ++mb)
#pragma unroll
    for (int i = 0; i < 4; ++i) ebe[mb][i] = __expf(be[16 * mb + 4 * q + i]);

  // ---- init P: exact alpha_0 for segment 0; uniform elsewhere ----
  half4_t P[4];
#pragma unroll
  for (int kb = 0; kb < 4; ++kb) {
    half4_t p;
#pragma unroll
    for (int i = 0; i < 4; ++i) p[i] = (half1_t)1.0f;
    P[kb] = p;
  }
  int sacc = 0, eprev = 0;
  if (h == 0 && wid == 0) {
    float pv[4][4];
    float m0 = 0.f;
#pragma unroll
    for (int kb = 0; kb < 4; ++kb)
#pragma unroll
      for (int i = 0; i < 4; ++i) {
        const int cls = 16 * kb + 4 * q + i;
        const float vv = __expf(xbase[cls] + bs[cls]);
        pv[kb][i] = vv;
        m0 = fmaxf(m0, vv);
      }
    m0 = chain_max(m0);
    const int e0 = ((__float_as_uint(m0) >> 23) & 255) - 127;
    const float sc0 = __uint_as_float((unsigned)(127 - e0) << 23);
    if (r == 0) {
#pragma unroll
      for (int kb = 0; kb < 4; ++kb) {
        half4_t p;
#pragma unroll
        for (int i = 0; i < 4; ++i) p[i] = (half1_t)(pv[kb][i] * sc0);
        P[kb] = p;
      }
      sacc = e0;
    }
  }

  // ---- path-energy emissions from OWN wave's staged LDS rows ----
  float pe;
  {
    pe = peu1;
    if (t0 >= 1) pe += peu0;
    if (t0 == 0) {
      pe += xbase[y0] + bs[y0];
    } else {
      const int e = t0 - R1 + eoff;
      const int sw = ((e >> 4) & 7) << 4;
      const half1_t ev = *reinterpret_cast<const half1_t*>(
          els + e * kRowStride + ((((y0 >> 2) * 8) ^ sw) + (y0 & 3) * 2));
      pe += __logf((float)ev);
    }
    {
      const int e = t0 + 1 - R1 + eoff;
      const int sw = ((e >> 4) & 7) << 4;
      const half1_t ev = *reinterpret_cast<const half1_t*>(
          els + e * kRowStride + ((((y1 >> 2) * 8) ^ sw) + (y1 & 3) * 2));
      pe += __logf((float)ev);
    }
    if (t0 + 1 == kT - 1) pe += be[y1];
    pe = wave_sum(pe);           // all lanes hold the wave's PE partial
  }

  // ---- phase 2: 12 lockstep steps (reads only own wave's rows) ----
  float ref = 0.f, fin = 0.f;
  const int ebase = 128 * wid + 8 * r;   // + s = LDS row

#pragma unroll
  for (int s = 0; s < kSteps; ++s) {
    int e = ebase + s;
    e = (e < elo) ? elo : e;
    e = (e > ehi) ? ehi : e;
    const int sw = ((e >> 4) & 7) << 4;
    const char* rowp = els + e * kRowStride;
    uint2 Eh[4];
#pragma unroll
    for (int kb = 0; kb < 4; ++kb)
      Eh[kb] = *reinterpret_cast<const uint2*>(rowp + (((kb * 32) + q * 8) ^ sw));

    f32x4 D[4];
#pragma unroll
    for (int mb = 0; mb < 4; ++mb) {
      f32x4 d = {0.f, 0.f, 0.f, 0.f};
#pragma unroll
      for (int kb = 0; kb < 4; ++kb)
        d = __builtin_amdgcn_mfma_f32_16x16x16f16(W[mb][kb], P[kb], d, 0, 0, 0);
      D[mb] = d;
    }

    const float sc = __uint_as_float((unsigned)(127 - eprev) << 23);
    const bool active = !((c == 0 && s < 4) || (c == 127 && s == kSteps - 1));

    float m = 0.f;
    half4_t Pn[4];
#pragma unroll
    for (int mb = 0; mb < 4; ++mb) {
      const half4_t eh = __builtin_bit_cast(half4_t, Eh[mb]);
      half4_t p;
#pragma unroll
      for (int i = 0; i < 4; ++i) {
        float st = D[mb][i] * sc * (float)eh[i];
        if (s == 10) st *= (c == 127) ? ebe[mb][i] : 1.f;  // be on t=1023
        m = fmaxf(m, st);
        p[i] = (half1_t)st;
      }
      Pn[mb] = p;
    }
#pragma unroll
    for (int mb = 0; mb < 4; ++mb) P[mb] = active ? Pn[mb] : P[mb];
    sacc += active ? (eprev + 2) : 0;     // +2 compensates W/4

    m = chain_max(m);   // off serial path: gates next step's scale only
    const int en = ((__float_as_uint(m) >> 23) & 255) - 127;
    eprev = active ? en : eprev;

    if (s == 3 || s == kSteps - 1) {      // burn-in end / final snapshot
      float Sv = 0.f;
#pragma unroll
      for (int mb = 0; mb < 4; ++mb)
#pragma unroll
        for (int i = 0; i < 4; ++i) Sv += (float)P[mb][i];
      Sv = chain_sum(Sv);
      const float lg = __log2f(Sv) + (float)sacc;
      if (s == 3) ref = (c == 0) ? 0.f : lg;
      else        fin = lg;
    }
  }

  // ---- fused output: one atomic per wave ----
  float val = (q == 0) ? (fin - ref) : 0.f;
  val = wave_sum(val);
  if (j == 0)
    atomicAdd(&out[b], 0.69314718055994531f * val - pe);
}

}  // namespace

extern "C" void kernel_launch(void* const* d_in, const int* in_sizes, int n_in,
                              void* d_out, int out_size, void* d_ws, size_t ws_size,
                              hipStream_t stream) {
  const float* x  = (const float*)d_in[0];
  const float* U  = (const float*)d_in[1];
  const float* bs = (const float*)d_in[2];
  const float* be = (const float*)d_in[3];
  const int*   y  = (const int*)d_in[4];
  float* out = (float*)d_out;

  hipMemsetAsync(out, 0, (size_t)out_size * sizeof(float), stream);
  crf_fused<<<512, 256, 0, stream>>>(x, U, bs, be, y, out);
}

// Round 21
// 29.733 us; speedup vs baseline: 1.0005x; 1.0005x over previous
//
#include <hip/hip_runtime.h>

namespace {

constexpr int kB = 256;
constexpr int kT = 1024;
constexpr int kC = 64;
constexpr int kSteps = 11;        // 3 burn-in + 8 span
constexpr int kRowStride = 136;   // 128B f16 row + 8B pad
constexpr int kMaxRows = 516;

typedef _Float16 half1_t;
typedef _Float16 half4_t __attribute__((ext_vector_type(4)));
typedef float    f32x4  __attribute__((ext_vector_type(4)));

__device__ __forceinline__ float wave_sum(float v) {
#pragma unroll
  for (int off = 32; off >= 1; off >>= 1) v += __shfl_xor(v, off, 64);
  return v;
}
// reduce across the 4 lanes {l, l^16, l^32, l^48} holding one column
__device__ __forceinline__ float chain_max(float v) {
  v = fmaxf(v, __shfl_xor(v, 16, 64));
  v = fmaxf(v, __shfl_xor(v, 32, 64));
  return v;
}
__device__ __forceinline__ float chain_sum(float v) {
  v += __shfl_xor(v, 16, 64);
  v += __shfl_xor(v, 32, 64);
  return v;
}

// 512 blocks x 256 threads. Block (b,h): batch b, segments 64h..64h+63.
// Staging (r19-proven dense form): E = exp(x) -> LDS f16 swizzled, one
//   32-deep burst of block-dense 16B loads + small tail; block barrier.
//   h=0: t in [1,512] at e=t+2 (elo 3, ehi 514); h=1: t in [510,1023] at
//   e=t-510 (elo 0, ehi 513). LDS row for (wid,r,s): e = 128*wid + 8*r + s.
// Phase 2 (step math verified r12-r20, absmax 0.0): 11 lockstep steps,
//   burn-in 3; D[mb] = sum_kb mfma_16x16x16f16(W'[mb][kb], P[kb]);
//   P = cvt_f16(D*sc*E); delay-1 dead-beat pow2 renorm; W' = exp(U)/4,
//   sacc += eprev+2 per active step.
// Path energy fused (LDS emissions); output fused: 1 atomicAdd per wave
//   into out[b] (zeroed by memsetAsync; r20-proven pattern).
__global__ __launch_bounds__(256) void crf_fused(
    const float* __restrict__ x,    // [B,T,C]
    const float* __restrict__ U,    // [C,C]
    const float* __restrict__ bs,   // [C]
    const float* __restrict__ be,   // [C]
    const int*   __restrict__ y,    // [B,T]
    float*       __restrict__ out)  // [B] accumulated
{
  const int bid = blockIdx.x;
  const int tid = threadIdx.x;
  const int wid = tid >> 6;
  const int j   = tid & 63;

  __shared__ __align__(16) char els[kMaxRows * kRowStride];  // 70176 B

  const int b    = bid >> 1;
  const int h    = bid & 1;
  const int R1   = h ? 510 : 1;    // t of source row 0
  const int elo  = h ? 0 : 3;
  const int ehi  = h ? 513 : 514;
  const int eoff = h ? 0 : 3;      // e = (t - R1) + eoff

  const float* xbase = x + (size_t)b * kT * kC;

  // ---- path-energy index loads (issued early) ----
  const int t0 = 512 * h + 2 * tid;
  const int* yrow = y + (size_t)b * kT;
  const int ym = (t0 > 0) ? yrow[t0 - 1] : 0;
  const int y0 = yrow[t0];
  const int y1 = yrow[t0 + 1];

  // ---- staging: 32-deep burst of block-dense 16B loads ----
  {
    const float* xs = xbase + (size_t)R1 * kC;
    f32x4 v[32];
#pragma unroll
    for (int u = 0; u < 32; ++u)
      v[u] = *reinterpret_cast<const f32x4*>(xs + (size_t)(u * 256 + tid) * 4);
#pragma unroll
    for (int u = 0; u < 32; ++u) {
      const int idx = u * 256 + tid;
      half4_t hv;
      hv[0] = (half1_t)__expf(v[u][0]);
      hv[1] = (half1_t)__expf(v[u][1]);
      hv[2] = (half1_t)__expf(v[u][2]);
      hv[3] = (half1_t)__expf(v[u][3]);
      const int e  = (idx >> 4) + eoff;
      const int k0 = idx & 15;
      const int sw = ((e >> 4) & 7) << 4;
      *reinterpret_cast<half4_t*>(els + e * kRowStride + ((k0 * 8) ^ sw)) = hv;
    }
    if (h && tid < 32) {   // tail: chunks 8192..8223 (rows 512..513)
      const int idx = 8192 + tid;
      const f32x4 v2 = *reinterpret_cast<const f32x4*>(xs + (size_t)idx * 4);
      half4_t hv;
      hv[0] = (half1_t)__expf(v2[0]);
      hv[1] = (half1_t)__expf(v2[1]);
      hv[2] = (half1_t)__expf(v2[2]);
      hv[3] = (half1_t)__expf(v2[3]);
      const int e  = idx >> 4;
      const int k0 = idx & 15;
      const int sw = ((e >> 4) & 7) << 4;
      *reinterpret_cast<half4_t*>(els + e * kRowStride + ((k0 * 8) ^ sw)) = hv;
    }
  }

  // path-energy U terms (L1/L2-hot)
  const float peu1 = U[y0 * kC + y1];
  const float peu0 = U[ym * kC + y0];

  const int q = j >> 4;       // k/m quad selector
  const int r = j & 15;       // MFMA column = segment-within-wave
  const int c = 64 * h + 16 * wid + r;    // global segment id 0..127

  // ---- W' A-fragments: A[m=r][k=4q+i] of (mb,kb) = exp(U[16kb+k][16mb+m])/4
  half4_t W[4][4];
#pragma unroll
  for (int mb = 0; mb < 4; ++mb)
#pragma unroll
    for (int kb = 0; kb < 4; ++kb) {
      half4_t w;
#pragma unroll
      for (int i = 0; i < 4; ++i)
        w[i] = (half1_t)(0.25f * __expf(U[(16 * kb + 4 * q + i) * kC + 16 * mb + r]));
      W[mb][kb] = w;
    }

  float ebe[4][4];
#pragma unroll
  for (int mb = 0; mb < 4; ++mb)
#pragma unroll
    for (int i = 0; i < 4; ++i) ebe[mb][i] = __expf(be[16 * mb + 4 * q + i]);

  // ---- init P: exact alpha_0 for segment 0; uniform elsewhere ----
  half4_t P[4];
#pragma unroll
  for (int kb = 0; kb < 4; ++kb) {
    half4_t p;
#pragma unroll
    for (int i = 0; i < 4; ++i) p[i] = (half1_t)1.0f;
    P[kb] = p;
  }
  int sacc = 0, eprev = 0;
  if (h == 0 && wid == 0) {
    float pv[4][4];
    float m0 = 0.f;
#pragma unroll
    for (int kb = 0; kb < 4; ++kb)
#pragma unroll
      for (int i = 0; i < 4; ++i) {
        const int cls = 16 * kb + 4 * q + i;
        const float vv = __expf(xbase[cls] + bs[cls]);
        pv[kb][i] = vv;
        m0 = fmaxf(m0, vv);
      }
    m0 = chain_max(m0);
    const int e0 = ((__float_as_uint(m0) >> 23) & 255) - 127;
    const float sc0 = __uint_as_float((unsigned)(127 - e0) << 23);
    if (r == 0) {
#pragma unroll
      for (int kb = 0; kb < 4; ++kb) {
        half4_t p;
#pragma unroll
        for (int i = 0; i < 4; ++i) p[i] = (half1_t)(pv[kb][i] * sc0);
        P[kb] = p;
      }
      sacc = e0;
    }
  }

  __syncthreads();

  // ---- path-energy emissions from staged LDS E ----
  float pe;
  {
    pe = peu1;
    if (t0 >= 1) pe += peu0;
    if (t0 == 0) {
      pe += xbase[y0] + bs[y0];
    } else {
      const int e = t0 - R1 + eoff;
      const int sw = ((e >> 4) & 7) << 4;
      const half1_t ev = *reinterpret_cast<const half1_t*>(
          els + e * kRowStride + ((((y0 >> 2) * 8) ^ sw) + (y0 & 3) * 2));
      pe += __logf((float)ev);
    }
    {
      const int e = t0 + 1 - R1 + eoff;
      const int sw = ((e >> 4) & 7) << 4;
      const half1_t ev = *reinterpret_cast<const half1_t*>(
          els + e * kRowStride + ((((y1 >> 2) * 8) ^ sw) + (y1 & 3) * 2));
      pe += __logf((float)ev);
    }
    if (t0 + 1 == kT - 1) pe += be[y1];
    pe = wave_sum(pe);           // all lanes hold the wave's PE partial
  }

  // ---- phase 2: 11 lockstep steps ----
  float ref = 0.f, fin = 0.f;
  const int ebase = 128 * wid + 8 * r;   // + s = LDS row

#pragma unroll
  for (int s = 0; s < kSteps; ++s) {
    int e = ebase + s;
    e = (e < elo) ? elo : e;
    e = (e > ehi) ? ehi : e;
    const int sw = ((e >> 4) & 7) << 4;
    const char* rowp = els + e * kRowStride;
    uint2 Eh[4];
#pragma unroll
    for (int kb = 0; kb < 4; ++kb)
      Eh[kb] = *reinterpret_cast<const uint2*>(rowp + (((kb * 32) + q * 8) ^ sw));

    f32x4 D[4];
#pragma unroll
    for (int mb = 0; mb < 4; ++mb) {
      f32x4 d = {0.f, 0.f, 0.f, 0.f};
#pragma unroll
      for (int kb = 0; kb < 4; ++kb)
        d = __builtin_amdgcn_mfma_f32_16x16x16f16(W[mb][kb], P[kb], d, 0, 0, 0);
      D[mb] = d;
    }

    const float sc = __uint_as_float((unsigned)(127 - eprev) << 23);
    const bool active = !((c == 0 && s < 3) || (c == 127 && s == kSteps - 1));

    float m = 0.f;
    half4_t Pn[4];
#pragma unroll
    for (int mb = 0; mb < 4; ++mb) {
      const half4_t eh = __builtin_bit_cast(half4_t, Eh[mb]);
      half4_t p;
#pragma unroll
      for (int i = 0; i < 4; ++i) {
        float st = D[mb][i] * sc * (float)eh[i];
        if (s == 9) st *= (c == 127) ? ebe[mb][i] : 1.f;  // be on t=1023
        m = fmaxf(m, st);
        p[i] = (half1_t)st;
      }
      Pn[mb] = p;
    }
#pragma unroll
    for (int mb = 0; mb < 4; ++mb) P[mb] = active ? Pn[mb] : P[mb];
    sacc += active ? (eprev + 2) : 0;     // +2 compensates W/4

    m = chain_max(m);   // off serial path: gates next step's scale only
    const int en = ((__float_as_uint(m) >> 23) & 255) - 127;
    eprev = active ? en : eprev;

    if (s == 2 || s == kSteps - 1) {      // burn-in end / final snapshot
      float Sv = 0.f;
#pragma unroll
      for (int mb = 0; mb < 4; ++mb)
#pragma unroll
        for (int i = 0; i < 4; ++i) Sv += (float)P[mb][i];
      Sv = chain_sum(Sv);
      const float lg = __log2f(Sv) + (float)sacc;
      if (s == 2) ref = (c == 0) ? 0.f : lg;
      else        fin = lg;
    }
  }

  // ---- fused output: one atomic per wave ----
  float val = (q == 0) ? (fin - ref) : 0.f;
  val = wave_sum(val);
  if (j == 0)
    atomicAdd(&out[b], 0.69314718055994531f * val - pe);
}

}  // namespace

extern "C" void kernel_launch(void* const* d_in, const int* in_sizes, int n_in,
                              void* d_out, int out_size, void* d_ws, size_t ws_size,
                              hipStream_t stream) {
  const float* x  = (const float*)d_in[0];
  const float* U  = (const float*)d_in[1];
  const float* bs = (const float*)d_in[2];
  const float* be = (const float*)d_in[3];
  const int*   y  = (const int*)d_in[4];
  float* out = (float*)d_out;

  hipMemsetAsync(out, 0, (size_t)out_size * sizeof(float), stream);
  crf_fused<<<512, 256, 0, stream>>>(x, U, bs, be, y, out);
}

// Round 22
// 26.725 us; speedup vs baseline: 1.1132x; 1.1126x over previous
//
#include <hip/hip_runtime.h>

namespace {

constexpr int kB = 256;
constexpr int kT = 1024;
constexpr int kC = 64;
constexpr int kSteps = 7;         // 3 burn-in + 4 span
constexpr int kRowStride = 136;   // 128B f16 row + 8B pad
constexpr int kMaxRows = 259;

typedef _Float16 half1_t;
typedef _Float16 half4_t __attribute__((ext_vector_type(4)));
typedef float    f32x4  __attribute__((ext_vector_type(4)));

__device__ __forceinline__ float wave_sum(float v) {
#pragma unroll
  for (int off = 32; off >= 1; off >>= 1) v += __shfl_xor(v, off, 64);
  return v;
}
// reduce across the 4 lanes {l, l^16, l^32, l^48} holding one column
__device__ __forceinline__ float chain_max(float v) {
  v = fmaxf(v, __shfl_xor(v, 16, 64));
  v = fmaxf(v, __shfl_xor(v, 32, 64));
  return v;
}
__device__ __forceinline__ float chain_sum(float v) {
  v += __shfl_xor(v, 16, 64);
  v += __shfl_xor(v, 32, 64);
  return v;
}

// ws floats: per batch, row of 272: val[c] c=0..255; pe partials 256..271.

// 1024 blocks x 256 threads. Block (b,g): batch b, segments 64g..64g+63
// (4 waves x 16 columns, span 4, burn-in 3). 35 KB LDS -> 4 blocks/CU
// (16 waves/CU vs r19's 8 -- the occupancy lever).
// Staging: E = exp(x) -> LDS f16 swizzled. g=0: t in [1,256] at e=t+2;
//   g>0: t in [256g-2, min(256(g+1),1023)] at e=t-(256g-2).
// Unified t = 4c + s - 2; LDS row e = 64*wid + 4*r + s (clamped [elo,ehi]).
// Step math verified r12-r21 (absmax 0.0): D[mb]=sum_kb mfma(W'[mb][kb],P[kb]);
// P=cvt_f16(D*sc*E); delay-1 dead-beat pow2 renorm; W'=exp(U)/4; sacc+=eprev+2.
// Masks: (c==0 && s<3) exact-init hold; (c==255 && s==6) t=1024 invalid;
// be factor at s==5 for c==255 (t=1023). PE fused: 1 timestep/thread,
// emission ln(E) from LDS, 16 wave-partials/batch. Output via separate
// combine kernel (r20/r21 measured: memset+atomic fusion costs +3 us).
__global__ __launch_bounds__(256) void crf_fused(
    const float* __restrict__ x,    // [B,T,C]
    const float* __restrict__ U,    // [C,C]
    const float* __restrict__ bs,   // [C]
    const float* __restrict__ be,   // [C]
    const int*   __restrict__ y,    // [B,T]
    float*       __restrict__ wsf)
{
  const int bid = blockIdx.x;
  const int tid = threadIdx.x;
  const int wid = tid >> 6;
  const int j   = tid & 63;

  __shared__ __align__(16) char els[kMaxRows * kRowStride];  // 35224 B

  const int b = bid >> 2;
  const int g = bid & 3;
  const int R1   = (g == 0) ? 1 : (256 * g - 2);
  const int rows = (g == 0) ? 256 : ((g == 3) ? 258 : 259);
  const int eoff = (g == 0) ? 3 : 0;
  const int elo  = eoff;
  const int ehi  = eoff + rows - 1;   // 258 / 258 / 258 / 257

  const float* xbase = x + (size_t)b * kT * kC;

  // ---- path-energy index loads (issued early) ----
  const int t0 = 256 * g + tid;
  const int* yrow = y + (size_t)b * kT;
  const int ym = (t0 > 0) ? yrow[t0 - 1] : 0;
  const int y0 = yrow[t0];

  // ---- staging: 16-deep dense burst + small tail ----
  {
    const float* xs = xbase + (size_t)R1 * kC;
    const int tail = rows * 16 - 4096;    // 0 / 48 / 48 / 32
    f32x4 vt;
    const bool hasTail = tid < tail;
    if (hasTail)
      vt = *reinterpret_cast<const f32x4*>(xs + (size_t)(4096 + tid) * 4);
    f32x4 v[16];
#pragma unroll
    for (int u = 0; u < 16; ++u)
      v[u] = *reinterpret_cast<const f32x4*>(xs + (size_t)(u * 256 + tid) * 4);
#pragma unroll
    for (int u = 0; u < 16; ++u) {
      const int idx = u * 256 + tid;
      half4_t hv;
      hv[0] = (half1_t)__expf(v[u][0]);
      hv[1] = (half1_t)__expf(v[u][1]);
      hv[2] = (half1_t)__expf(v[u][2]);
      hv[3] = (half1_t)__expf(v[u][3]);
      const int e  = (idx >> 4) + eoff;
      const int k0 = idx & 15;
      const int sw = ((e >> 4) & 7) << 4;
      *reinterpret_cast<half4_t*>(els + e * kRowStride + ((k0 * 8) ^ sw)) = hv;
    }
    if (hasTail) {
      const int idx = 4096 + tid;
      half4_t hv;
      hv[0] = (half1_t)__expf(vt[0]);
      hv[1] = (half1_t)__expf(vt[1]);
      hv[2] = (half1_t)__expf(vt[2]);
      hv[3] = (half1_t)__expf(vt[3]);
      const int e  = (idx >> 4) + eoff;
      const int k0 = idx & 15;
      const int sw = ((e >> 4) & 7) << 4;
      *reinterpret_cast<half4_t*>(els + e * kRowStride + ((k0 * 8) ^ sw)) = hv;
    }
  }

  // path-energy transition term (L1/L2-hot)
  const float peu = U[ym * kC + y0];

  const int q = j >> 4;       // k/m quad selector
  const int r = j & 15;       // MFMA column = segment-within-wave
  const int c = 64 * g + 16 * wid + r;    // global segment id 0..255

  // ---- W' A-fragments: A[m=r][k=4q+i] of (mb,kb) = exp(U[16kb+k][16mb+m])/4
  half4_t W[4][4];
#pragma unroll
  for (int mb = 0; mb < 4; ++mb)
#pragma unroll
    for (int kb = 0; kb < 4; ++kb) {
      half4_t w;
#pragma unroll
      for (int i = 0; i < 4; ++i)
        w[i] = (half1_t)(0.25f * __expf(U[(16 * kb + 4 * q + i) * kC + 16 * mb + r]));
      W[mb][kb] = w;
    }

  float ebe[4][4];
#pragma unroll
  for (int mb = 0; mb < 4; ++mb)
#pragma unroll
    for (int i = 0; i < 4; ++i) ebe[mb][i] = __expf(be[16 * mb + 4 * q + i]);

  // ---- init P: exact alpha_0 for segment 0; uniform elsewhere ----
  half4_t P[4];
#pragma unroll
  for (int kb = 0; kb < 4; ++kb) {
    half4_t p;
#pragma unroll
    for (int i = 0; i < 4; ++i) p[i] = (half1_t)1.0f;
    P[kb] = p;
  }
  int sacc = 0, eprev = 0;
  if (g == 0 && wid == 0) {
    float pv[4][4];
    float m0 = 0.f;
#pragma unroll
    for (int kb = 0; kb < 4; ++kb)
#pragma unroll
      for (int i = 0; i < 4; ++i) {
        const int cls = 16 * kb + 4 * q + i;
        const float vv = __expf(xbase[cls] + bs[cls]);
        pv[kb][i] = vv;
        m0 = fmaxf(m0, vv);
      }
    m0 = chain_max(m0);
    const int e0 = ((__float_as_uint(m0) >> 23) & 255) - 127;
    const float sc0 = __uint_as_float((unsigned)(127 - e0) << 23);
    if (r == 0) {
#pragma unroll
      for (int kb = 0; kb < 4; ++kb) {
        half4_t p;
#pragma unroll
        for (int i = 0; i < 4; ++i) p[i] = (half1_t)(pv[kb][i] * sc0);
        P[kb] = p;
      }
      sacc = e0;
    }
  }

  __syncthreads();

  // ---- path energy: 1 timestep/thread, emission from staged LDS ----
  float pe;
  {
    pe = 0.f;
    if (t0 >= 1) pe += peu;
    if (t0 == 0) {
      pe += xbase[y0] + bs[y0];
    } else {
      const int e = t0 - R1 + eoff;
      const int sw = ((e >> 4) & 7) << 4;
      const half1_t ev = *reinterpret_cast<const half1_t*>(
          els + e * kRowStride + ((((y0 >> 2) * 8) ^ sw) + (y0 & 3) * 2));
      pe += __logf((float)ev);
    }
    if (t0 == kT - 1) pe += be[y0];
    pe = wave_sum(pe);
    if (j == 0) wsf[(size_t)b * 272 + 256 + g * 4 + wid] = pe;
  }

  // ---- phase 2: 7 lockstep steps ----
  float ref = 0.f, fin = 0.f;
  const int ebase = 64 * wid + 4 * r;   // + s = LDS row

#pragma unroll
  for (int s = 0; s < kSteps; ++s) {
    int e = ebase + s;
    e = (e < elo) ? elo : e;
    e = (e > ehi) ? ehi : e;
    const int sw = ((e >> 4) & 7) << 4;
    const char* rowp = els + e * kRowStride;
    uint2 Eh[4];
#pragma unroll
    for (int kb = 0; kb < 4; ++kb)
      Eh[kb] = *reinterpret_cast<const uint2*>(rowp + (((kb * 32) + q * 8) ^ sw));

    f32x4 D[4];
#pragma unroll
    for (int mb = 0; mb < 4; ++mb) {
      f32x4 d = {0.f, 0.f, 0.f, 0.f};
#pragma unroll
      for (int kb = 0; kb < 4; ++kb)
        d = __builtin_amdgcn_mfma_f32_16x16x16f16(W[mb][kb], P[kb], d, 0, 0, 0);
      D[mb] = d;
    }

    const float sc = __uint_as_float((unsigned)(127 - eprev) << 23);
    const bool active = !((c == 0 && s < 3) || (c == 255 && s == kSteps - 1));

    float m = 0.f;
    half4_t Pn[4];
#pragma unroll
    for (int mb = 0; mb < 4; ++mb) {
      const half4_t eh = __builtin_bit_cast(half4_t, Eh[mb]);
      half4_t p;
#pragma unroll
      for (int i = 0; i < 4; ++i) {
        float st = D[mb][i] * sc * (float)eh[i];
        if (s == 5) st *= (c == 255) ? ebe[mb][i] : 1.f;  // be on t=1023
        m = fmaxf(m, st);
        p[i] = (half1_t)st;
      }
      Pn[mb] = p;
    }
#pragma unroll
    for (int mb = 0; mb < 4; ++mb) P[mb] = active ? Pn[mb] : P[mb];
    sacc += active ? (eprev + 2) : 0;     // +2 compensates W/4

    m = chain_max(m);   // off serial path: gates next step's scale only
    const int en = ((__float_as_uint(m) >> 23) & 255) - 127;
    eprev = active ? en : eprev;

    if (s == 2 || s == kSteps - 1) {      // burn-in end / final snapshot
      float Sv = 0.f;
#pragma unroll
      for (int mb = 0; mb < 4; ++mb)
#pragma unroll
        for (int i = 0; i < 4; ++i) Sv += (float)P[mb][i];
      Sv = chain_sum(Sv);
      const float lg = __log2f(Sv) + (float)sacc;
      if (s == 2) ref = (c == 0) ? 0.f : lg;
      else        fin = lg;
    }
  }

  if (q == 0) wsf[(size_t)b * 272 + c] = fin - ref;   // coalesced 16-lane write
}

// out[b] = ln2 * sum_c val[b][c] - sum of 16 pe partials (contiguous row)
__global__ __launch_bounds__(64, 1) void crf_combine(
    const float* __restrict__ wsf, float* __restrict__ out)
{
  const int b = blockIdx.x;
  const int j = threadIdx.x & 63;

  const float* row = wsf + (size_t)b * 272;
  float v = 0.69314718055994531f *
            (row[j] + row[j + 64] + row[j + 128] + row[j + 192]);
  if (j < 16) v -= row[256 + j];
  v = wave_sum(v);

  if (j == 0) out[b] = v;
}

}  // namespace

extern "C" void kernel_launch(void* const* d_in, const int* in_sizes, int n_in,
                              void* d_out, int out_size, void* d_ws, size_t ws_size,
                              hipStream_t stream) {
  const float* x  = (const float*)d_in[0];
  const float* U  = (const float*)d_in[1];
  const float* bs = (const float*)d_in[2];
  const float* be = (const float*)d_in[3];
  const int*   y  = (const int*)d_in[4];
  float* out = (float*)d_out;
  float* wsf = (float*)d_ws;

  crf_fused<<<1024, 256, 0, stream>>>(x, U, bs, be, y, wsf);
  crf_combine<<<kB, 64, 0, stream>>>(wsf, out);
}